// Round 2
// 4606.626 us; speedup vs baseline: 1.5593x; 1.5593x over previous
//
#include <hip/hip_runtime.h>
#include <hip/hip_bf16.h>
#include <math.h>

// Problem constants
static constexpr int Bb = 8, Tt = 512, Ee = 512, Hh = 1024, Vv = 32000;
static constexpr int BT = Bb * Tt;  // 4096

typedef __attribute__((ext_vector_type(8))) short s8v;   // 8 bf16 (4 VGPRs) MFMA operand
typedef __attribute__((ext_vector_type(4))) float f4v;   // MFMA accumulator

__device__ __forceinline__ unsigned short f2bf(float x) {
  union { float f; unsigned u; } v; v.f = x;
  unsigned r = v.u + 0x7FFFu + ((v.u >> 16) & 1u);  // RNE
  return (unsigned short)(r >> 16);
}
__device__ __forceinline__ float bf2f(unsigned short h) {
  union { unsigned u; float f; } v; v.u = ((unsigned)h) << 16;
  return v.f;
}

// ---------------------------------------------------------------- embedding
// embB[r][e] = bf16(wte[idx[r]][e]),  r = b*T+t
__global__ __launch_bounds__(256) void k_embed(const int* __restrict__ idx,
                                               const float* __restrict__ wte,
                                               unsigned short* __restrict__ embB) {
  int g = blockIdx.x * 256 + threadIdx.x;     // 0 .. 524287 (float4 chunks)
  int r = g >> 7;                             // 128 float4 per 512-wide row
  int c4 = (g & 127) * 4;
  float4 v = *(const float4*)(wte + (size_t)idx[r] * Ee + c4);
  *(ushort4*)(embB + (size_t)r * Ee + c4) =
      make_ushort4(f2bf(v.x), f2bf(v.y), f2bf(v.z), f2bf(v.w));
}

// ------------------------------------------------- transpose f32 -> bf16 [C][R]
__global__ __launch_bounds__(256) void k_transpose(const float* __restrict__ src,
                                                   unsigned short* __restrict__ dst,
                                                   int R, int C) {
  __shared__ float tile[32][33];
  int c0 = blockIdx.x * 32, r0 = blockIdx.y * 32;
  int tx = threadIdx.x, ty = threadIdx.y;
#pragma unroll
  for (int i = 0; i < 4; i++)
    tile[ty + i * 8][tx] = src[(size_t)(r0 + ty + i * 8) * C + c0 + tx];
  __syncthreads();
#pragma unroll
  for (int i = 0; i < 4; i++)
    dst[(size_t)(c0 + ty + i * 8) * R + r0 + tx] = f2bf(tile[tx][ty + i * 8]);
}

// ---------------------------------------------------------------- h0 init (bf16)
__global__ void k_hinit(const float* __restrict__ start, unsigned short* __restrict__ hglobB) {
  int g = blockIdx.x * 256 + threadIdx.x;  // 8192
  hglobB[g] = f2bf(start[g & (Hh - 1)]);
}

// ---------------------------------------------------------------- GEMM
// C[M,N](f32 or bf16) = A[M,K]bf16 * Bt[N,K]bf16 + bias[N]
// 128x128 block tile, BK=64, 256 threads = 4 waves (2x2 of 64x64).
// LDS rows padded to 88 elems: stride 176 B (11*16 -> b128-aligned, bank stride 12 -> 2-way, free)
__global__ __launch_bounds__(256) void k_gemm(const unsigned short* __restrict__ A,
                                              const unsigned short* __restrict__ Bt,
                                              void* __restrict__ Cp,
                                              const float* __restrict__ bias,
                                              int K, int lda, int ldb, int ldc, int c_bf16) {
  __shared__ unsigned short As[128 * 88];
  __shared__ unsigned short Bs[128 * 88];
  const int m0 = blockIdx.x * 128, n0 = blockIdx.y * 128;
  const int tid = threadIdx.x;
  const int w = tid >> 6, lane = tid & 63, q = lane >> 4, l15 = lane & 15;
  const int wm = (w >> 1) * 64, wn = (w & 1) * 64;

  f4v acc[4][4];
#pragma unroll
  for (int i = 0; i < 4; i++)
#pragma unroll
    for (int j = 0; j < 4; j++) acc[i][j] = (f4v){0.f, 0.f, 0.f, 0.f};

  for (int k0 = 0; k0 < K; k0 += 64) {
#pragma unroll
    for (int i = 0; i < 4; i++) {  // stage 16KB A-tile + 16KB B-tile
      int cid = i * 256 + tid;
      int row = cid >> 3, c8 = (cid & 7) * 8;
      *(uint4*)(As + row * 88 + c8) = *(const uint4*)(A + (size_t)(m0 + row) * lda + k0 + c8);
      *(uint4*)(Bs + row * 88 + c8) = *(const uint4*)(Bt + (size_t)(n0 + row) * ldb + k0 + c8);
    }
    __syncthreads();
#pragma unroll
    for (int kt = 0; kt < 64; kt += 32) {
      s8v a[4], b[4];
#pragma unroll
      for (int mt = 0; mt < 4; mt++) a[mt] = *(const s8v*)(As + (wm + mt * 16 + l15) * 88 + kt + q * 8);
#pragma unroll
      for (int nt = 0; nt < 4; nt++) b[nt] = *(const s8v*)(Bs + (wn + nt * 16 + l15) * 88 + kt + q * 8);
#pragma unroll
      for (int mt = 0; mt < 4; mt++)
#pragma unroll
        for (int nt = 0; nt < 4; nt++)
          acc[mt][nt] = __builtin_amdgcn_mfma_f32_16x16x32_bf16(a[mt], b[nt], acc[mt][nt], 0, 0, 0);
    }
    __syncthreads();
  }
  // epilogue: D row = q*4+r, col = l15 (verified m89/m91 layout)
#pragma unroll
  for (int nt = 0; nt < 4; nt++) {
    int n = n0 + wn + nt * 16 + l15;
    float bv = bias[n];
#pragma unroll
    for (int mt = 0; mt < 4; mt++)
#pragma unroll
      for (int r = 0; r < 4; r++) {
        int m = m0 + wm + mt * 16 + q * 4 + r;
        float val = acc[mt][nt][r] + bv;
        if (c_bf16) ((unsigned short*)Cp)[(size_t)m * ldc + n] = f2bf(val);
        else        ((float*)Cp)[(size_t)m * ldc + n] = val;
      }
  }
}

// ---------------------------------------------------------------- GRU persistent kernel
// 64 blocks x 512 threads. Block bx owns output columns [bx*16, bx*16+16) of all 3 gates.
// LDS-resident U^T slices (bf16). Two device-scope barriers per timestep.
//
// Cross-block data (hglobB, vbuf, flag) uses RELAXED agent-scope atomics (sc1,
// LLC-coherent: bypass the non-coherent XCD L2) -> no buffer_wbl2 / buffer_inv
// cache maintenance on the critical path. Ordering: sc1 stores -> __syncthreads
// (s_waitcnt vmcnt(0) per wave => stores acked at LLC) -> relaxed flag add ->
// consumers poll relaxed -> s_barrier -> sc1 loads.
// Hang-proofing: if relaxed polls were ever served from a stale cache, the poll
// falls back to ACQUIRE loads (forced invalidate) after ~4096 sleeps.
#define NBGRU 64
#define UPAD 1048   // row stride: 2096 B = 131*16 (b128-aligned), bank stride 12 -> 2-way (free)

__device__ __forceinline__ void gru_barrier(unsigned* flag, unsigned target) {
  __syncthreads();  // drains vmcnt for all waves -> all sc1 stores acked at LLC
  if (threadIdx.x == 0) {
    __hip_atomic_fetch_add(flag, 1u, __ATOMIC_RELAXED, __HIP_MEMORY_SCOPE_AGENT);
    int spins = 0;
    while (__hip_atomic_load(flag, __ATOMIC_RELAXED, __HIP_MEMORY_SCOPE_AGENT) < target) {
      __builtin_amdgcn_s_sleep(1);
      if (++spins > 4096) {  // forward-progress fallback: acquire forces cache inv
        if (__hip_atomic_load(flag, __ATOMIC_ACQUIRE, __HIP_MEMORY_SCOPE_AGENT) >= target)
          break;
      }
    }
  }
  __syncthreads();
}

__global__ __launch_bounds__(512, 1) void k_gru(const unsigned short* __restrict__ UT,  // [3][1024][1024]
                                                const unsigned short* __restrict__ X,   // [4096][3072] bf16
                                                const float* __restrict__ start,        // [1][1024]
                                                unsigned short* __restrict__ hglobB,    // [8][1024] bf16
                                                unsigned short* __restrict__ vbuf,      // [8][1024] bf16
                                                unsigned short* __restrict__ hidB,      // [4096][1024] bf16
                                                unsigned* __restrict__ flag) {
  extern __shared__ char smem[];
  unsigned short* Ul  = (unsigned short*)smem;      // 3 * 16 * UPAD
  unsigned short* hsd = Ul + 3 * 16 * UPAD;         // 16 * UPAD (A-operand: h, then v)
  float* pacc = (float*)(hsd + 16 * UPAD);          // 8 waves * 8 m * 32 n
  float* zloc = pacc + 8 * 8 * 32;                  // 8*16
  float* hloc = zloc + 128;                         // 8*16  (own-slice f32 h for r*h)

  const int tid = threadIdx.x;
  const int c0 = blockIdx.x * 16;
  const int w = tid >> 6, lane = tid & 63, q = lane >> 4, l15 = lane & 15;
  const int kb = w * 128;  // K-split across 8 waves

  // Load U^T slices (coalesced): 16 rows x 1024 per gate
#pragma unroll
  for (int g = 0; g < 3; g++)
#pragma unroll
    for (int i = 0; i < 4; i++) {
      int cid = i * 512 + tid;  // 0..2047 16B-chunks
      int row = cid >> 7, c8 = (cid & 127) * 8;
      *(uint4*)(Ul + g * 16 * UPAD + row * UPAD + c8) =
          *(const uint4*)(UT + (size_t)g * 1048576 + (size_t)(c0 + row) * 1024 + c8);
    }

  // init own-slice f32 h: register hp (h-update thread) + hloc (for r*h threads)
  float hp = 0.f;
  if (tid < 128) {
    int b = tid >> 4, jj = tid & 15;
    hp = start[c0 + jj];
    hloc[b * 16 + jj] = hp;
  }

  for (int t = 0; t < Tt; t++) {
    // ---- X prefetch for this step (issued ~whole step ahead of use) ----
    float xa = 0.f, xh_ = 0.f;
    if (tid < 256) {
      int b = tid >> 5, c = tid & 31;
      int xr = (b * Tt + t) * 3072;
      xa = bf2f(c < 16 ? X[xr + c0 + c] : X[xr + 1024 + c0 + (c - 16)]);
    }
    if (tid < 128) {
      int b = tid >> 4, jj = tid & 15;
      xh_ = bf2f(X[(b * Tt + t) * 3072 + 2048 + c0 + jj]);
    }

    // ---- stage A: z,r ----
#pragma unroll
    for (int i = 0; i < 4; i++) {  // h (bf16, LLC) -> hsd ; 2048 x 8B chunks
      int cid = i * 512 + tid;
      int b = cid >> 8, c4 = (cid & 255) * 4;
      unsigned long long v = __hip_atomic_load(
          (const unsigned long long*)(hglobB + b * 1024 + c4),
          __ATOMIC_RELAXED, __HIP_MEMORY_SCOPE_AGENT);
      *(unsigned long long*)(hsd + b * UPAD + c4) = v;
    }
    __syncthreads();
    f4v az = {0.f, 0.f, 0.f, 0.f}, ar = {0.f, 0.f, 0.f, 0.f};
#pragma unroll
    for (int kk = 0; kk < 4; kk++) {
      int k = kb + kk * 32 + q * 8;
      s8v a  = *(const s8v*)(hsd + l15 * UPAD + k);
      s8v bz = *(const s8v*)(Ul + 0 * 16 * UPAD + l15 * UPAD + k);
      s8v br = *(const s8v*)(Ul + 1 * 16 * UPAD + l15 * UPAD + k);
      az = __builtin_amdgcn_mfma_f32_16x16x32_bf16(a, bz, az, 0, 0, 0);
      ar = __builtin_amdgcn_mfma_f32_16x16x32_bf16(a, br, ar, 0, 0, 0);
    }
    if (q < 2) {  // D rows 0..7 are the valid batch rows
#pragma unroll
      for (int r = 0; r < 4; r++) {
        pacc[(w * 8 + q * 4 + r) * 32 + l15]      = az[r];
        pacc[(w * 8 + q * 4 + r) * 32 + 16 + l15] = ar[r];
      }
    }
    __syncthreads();
    if (tid < 256) {  // reduce 8 wave-partials + activations
      int b = tid >> 5, c = tid & 31;
      float s = 0.f;
#pragma unroll
      for (int ww = 0; ww < 8; ww++) s += pacc[(ww * 8 + b) * 32 + c];
      if (c < 16) {
        zloc[b * 16 + c] = 1.f / (1.f + __expf(-(xa + s)));
      } else {
        int rc = c - 16;
        float rv = 1.f / (1.f + __expf(-(xa + s)));
        unsigned short myb = f2bf(rv * hloc[b * 16 + rc]);
        // pack lane pairs -> one 32-bit relaxed sc1 store per even rc
        unsigned nb = (unsigned)__shfl_down((int)myb, 1);
        if ((rc & 1) == 0) {
          unsigned packed = (unsigned)myb | (nb << 16);
          __hip_atomic_store((unsigned*)(vbuf + b * 1024 + c0 + rc), packed,
                             __ATOMIC_RELAXED, __HIP_MEMORY_SCOPE_AGENT);
        }
      }
    }
    gru_barrier(flag, (unsigned)NBGRU * (2 * t + 1));

    // ---- stage B: hbar, h update ----
#pragma unroll
    for (int i = 0; i < 4; i++) {  // v (bf16, LLC) -> hsd ; 2048 x 8B chunks
      int cid = i * 512 + tid;
      int b = cid >> 8, c4 = (cid & 255) * 4;
      unsigned long long v = __hip_atomic_load(
          (const unsigned long long*)(vbuf + b * 1024 + c4),
          __ATOMIC_RELAXED, __HIP_MEMORY_SCOPE_AGENT);
      *(unsigned long long*)(hsd + b * UPAD + c4) = v;
    }
    __syncthreads();
    f4v ah = {0.f, 0.f, 0.f, 0.f};
#pragma unroll
    for (int kk = 0; kk < 4; kk++) {
      int k = kb + kk * 32 + q * 8;
      s8v a  = *(const s8v*)(hsd + l15 * UPAD + k);
      s8v bh = *(const s8v*)(Ul + 2 * 16 * UPAD + l15 * UPAD + k);
      ah = __builtin_amdgcn_mfma_f32_16x16x32_bf16(a, bh, ah, 0, 0, 0);
    }
    if (q < 2)
#pragma unroll
      for (int r = 0; r < 4; r++) pacc[(w * 8 + q * 4 + r) * 32 + l15] = ah[r];
    __syncthreads();
    if (tid < 128) {
      int b = tid >> 4, jj = tid & 15;
      float s = 0.f;
#pragma unroll
      for (int ww = 0; ww < 8; ww++) s += pacc[(ww * 8 + b) * 32 + jj];
      float hbar = tanhf(xh_ + s);
      float z = zloc[b * 16 + jj];
      float hn = (1.f - z) * hp + z * hbar;
      hp = hn;
      hloc[b * 16 + jj] = hn;
      unsigned short hb = f2bf(hn);
      // pack lane pairs -> one 32-bit relaxed sc1 store per even jj
      unsigned nb = (unsigned)__shfl_down((int)hb, 1);
      if ((jj & 1) == 0) {
        unsigned packed = (unsigned)hb | (nb << 16);
        __hip_atomic_store((unsigned*)(hglobB + b * 1024 + c0 + jj), packed,
                           __ATOMIC_RELAXED, __HIP_MEMORY_SCOPE_AGENT);
      }
      hidB[(size_t)(b * Tt + t) * 1024 + c0 + jj] = hb;  // plain: consumed by later kernel
    }
    gru_barrier(flag, (unsigned)NBGRU * (2 * t + 2));
  }
}

// ---------------------------------------------------------------- loss
__global__ __launch_bounds__(256) void k_loss(const float* __restrict__ logits,
                                              const int* __restrict__ tgt,
                                              float* __restrict__ accum) {
  int r = blockIdx.x;
  const float* row = logits + (size_t)r * Vv;
  float m = -3.0e38f, s = 0.f;
  for (int i = threadIdx.x; i < Vv; i += 256) {  // online logsumexp
    float x = row[i];
    if (x > m) { s = s * __expf(m - x) + 1.f; m = x; }
    else       s += __expf(x - m);
  }
  for (int off = 32; off > 0; off >>= 1) {  // wave64 butterfly
    float mo = __shfl_down(m, off), so = __shfl_down(s, off);
    if (mo > m) { s = s * __expf(m - mo) + so; m = mo; }
    else        s += so * __expf(mo - m);
  }
  __shared__ float ms[4], ss[4];
  if ((threadIdx.x & 63) == 0) { ms[threadIdx.x >> 6] = m; ss[threadIdx.x >> 6] = s; }
  __syncthreads();
  if (threadIdx.x == 0) {
    m = ms[0]; s = ss[0];
    for (int i = 1; i < 4; i++) {
      float mo = ms[i], so = ss[i];
      if (mo > m) { s = s * __expf(m - mo) + so; m = mo; }
      else        s += so * __expf(mo - m);
    }
    atomicAdd(accum, logf(s) + m - row[tgt[r]]);
  }
}

__global__ void k_final(const float* __restrict__ accum, float* __restrict__ out) {
  out[(size_t)BT * Vv] = accum[0] * (1.f / (float)BT);
}

// ---------------------------------------------------------------- launcher
extern "C" void kernel_launch(void* const* d_in, const int* in_sizes, int n_in,
                              void* d_out, int out_size, void* d_ws, size_t ws_size,
                              hipStream_t stream) {
  const int*   idx   = (const int*)d_in[0];
  const int*   tgtp  = (const int*)d_in[1];
  const float* wte   = (const float*)d_in[2];
  const float* start = (const float*)d_in[3];
  const float* Wz    = (const float*)d_in[4];
  const float* bz    = (const float*)d_in[5];
  const float* Wr    = (const float*)d_in[6];
  const float* br    = (const float*)d_in[7];
  const float* Wh    = (const float*)d_in[8];
  const float* bh    = (const float*)d_in[9];
  const float* lmW   = (const float*)d_in[10];
  const float* lmb   = (const float*)d_in[11];

  // workspace layout (87,605,760 B total)
  char* ws = (char*)d_ws;
  if (ws_size < 87605760u) return;  // insufficient scratch -> bail (bench will flag)
  unsigned*       flag   = (unsigned*)ws;                        // +0
  float*          accum  = (float*)(ws + 128);                   // +128
  unsigned short* hglobB = (unsigned short*)(ws + 512);          // 16 KB bf16
  unsigned short* vbuf   = (unsigned short*)(ws + 33280);        // 16 KB
  unsigned short* embB   = (unsigned short*)(ws + 49664);        // 4 MB
  unsigned short* WxT    = (unsigned short*)(ws + 4243968);      // 3 MB  [3][1024][512]
  unsigned short* UT     = (unsigned short*)(ws + 7389696);      // 6 MB  [3][1024][1024]
  unsigned short* lmWT   = (unsigned short*)(ws + 13681152);     // 64 MB [32000][1024]
  unsigned short* hidB   = (unsigned short*)(ws + 79217152);     // 8 MB  [4096][1024]
  // X gates [4096][3072] bf16 (25 MB) live in d_out; consumed by GRU before LM head overwrites.
  unsigned short* Xp = (unsigned short*)d_out;

  hipMemsetAsync(d_ws, 0, 512, stream);  // zero flag + accum every launch

  k_embed<<<2048, 256, 0, stream>>>(idx, wte, embB);

  dim3 tb(32, 8);
  k_transpose<<<dim3(32, 16), tb, 0, stream>>>(Wz, WxT + 0 * 524288, 512, 1024);
  k_transpose<<<dim3(32, 16), tb, 0, stream>>>(Wr, WxT + 1 * 524288, 512, 1024);
  k_transpose<<<dim3(32, 16), tb, 0, stream>>>(Wh, WxT + 2 * 524288, 512, 1024);
  k_transpose<<<dim3(32, 32), tb, 0, stream>>>(Wz + 512 * 1024, UT + 0 * 1048576, 1024, 1024);
  k_transpose<<<dim3(32, 32), tb, 0, stream>>>(Wr + 512 * 1024, UT + 1 * 1048576, 1024, 1024);
  k_transpose<<<dim3(32, 32), tb, 0, stream>>>(Wh + 512 * 1024, UT + 2 * 1048576, 1024, 1024);
  k_transpose<<<dim3(1000, 32), tb, 0, stream>>>(lmW, lmWT, 1024, 32000);

  k_hinit<<<32, 256, 0, stream>>>(start, hglobB);

  // X gates: [4096,512] @ [512,1024] (+bias) -> bf16 into d_out at col offset g*1024
  const float* gb[3] = {bz, br, bh};
  for (int g = 0; g < 3; g++)
    k_gemm<<<dim3(32, 8), 256, 0, stream>>>(embB, WxT + g * 524288, (void*)(Xp + g * 1024),
                                            gb[g], 512, 512, 512, 3072, 1);

  // GRU scan: 143,360 B dynamic LDS (>64KB: set attribute defensively)
  static bool attr_set = [] {
    hipFuncSetAttribute((const void*)k_gru, hipFuncAttributeMaxDynamicSharedMemorySize, 143360);
    return true;
  }();
  (void)attr_set;
  k_gru<<<NBGRU, 512, 143360, stream>>>(UT, Xp, start, hglobB, vbuf, hidB, flag);

  // LM head: [4096,1024] @ [1024,32000] + lmb -> f32 logits in d_out
  k_gemm<<<dim3(32, 250), 256, 0, stream>>>(hidB, lmWT, d_out, lmb, 1024, 1024, 1024, 32000, 0);

  k_loss<<<4096, 256, 0, stream>>>((const float*)d_out, tgtp, accum);
  k_final<<<1, 1, 0, stream>>>(accum, (float*)d_out);
}